// Round 3
// baseline (539.800 us; speedup 1.0000x reference)
//
#include <hip/hip_runtime.h>

#define EDIM   4096
#define NHEAD  32
#define DHEAD  128
#define LCACHE 8191
#define LTOT   8192
#define NSPLIT 1024
#define RPB    8     // rows per split (NSPLIT*RPB == LTOT)

#define SCALE 0.08838834764831845f  // 1/sqrt(128)

typedef float __attribute__((ext_vector_type(4))) f32x4;

__device__ __forceinline__ f32x4 ntload4(const float* p) {
    return __builtin_nontemporal_load((const f32x4*)p);
}
__device__ __forceinline__ void ntstore4(float* p, f32x4 v) {
    __builtin_nontemporal_store(v, (f32x4*)p);
}
__device__ __forceinline__ f32x4 ld4(const float* p) {
    return *(const f32x4*)p;
}

// ---------------------------------------------------------------------------
// Kernel 1: q/k/v GEMVs (f32). grid 12288: sel = idx>>12, row = idx & 4095.
// Wk/Wv streamed non-temporal (read-once); Wq/seq temporal (reused by proj).
// ---------------------------------------------------------------------------
__global__ __launch_bounds__(256) void qkv_kernel(
    const float* __restrict__ seq,
    const float* __restrict__ Wq, const float* __restrict__ bq,
    const float* __restrict__ Wk, const float* __restrict__ bk,
    const float* __restrict__ Wv, const float* __restrict__ bv,
    float* __restrict__ q_f, float* __restrict__ out)
{
    int row = blockIdx.x & 4095;
    int sel = blockIdx.x >> 12;
    const float* W = sel == 0 ? Wq : (sel == 1 ? Wk : Wv);
    const float* b = sel == 0 ? bq : (sel == 1 ? bk : bv);
    const float* wr = W + (size_t)row * EDIM;
    int t = threadIdx.x;

    float sum = 0.f;
#pragma unroll
    for (int i = 0; i < 4; ++i) {
        int j = (i * 256 + t) * 4;
        f32x4 w = (sel == 0) ? ld4(wr + j) : ntload4(wr + j);
        f32x4 s = ld4(seq + j);
        sum += w.x * s.x + w.y * s.y + w.z * s.z + w.w * s.w;
    }
    for (int m = 32; m; m >>= 1) sum += __shfl_xor(sum, m);
    __shared__ float wsum[4];
    if ((t & 63) == 0) wsum[t >> 6] = sum;
    __syncthreads();
    if (t == 0) {
        float total = wsum[0] + wsum[1] + wsum[2] + wsum[3] + b[row];
        if (sel == 0)      q_f[row] = total;
        else if (sel == 1) out[(size_t)EDIM * (1 + LCACHE) + row] = total;
        else               out[(size_t)EDIM * (1 + LTOT + LCACHE) + row] = total;
    }
}

// ---------------------------------------------------------------------------
// Kernel 2: fused KV-copy + flash-decode partials.
// grid NSPLIT=1024, block 256.  Thread t: head h=t>>3, sublane sl=t&7,
// owns cols [16t,16t+16).  K pass: NT-read kc row, NT-write k_new, per-head
// dot (3 shuffles).  Per-head softmax over RPB=8 rows.  V pass: same + PV.
// pm/pl stored transposed [h][s] for coalesced combine reads.
// ---------------------------------------------------------------------------
__global__ __launch_bounds__(256) void fused_copy_attn(
    const float* __restrict__ kc, const float* __restrict__ vc,
    const float* __restrict__ q_f, float* __restrict__ out,
    float* __restrict__ pm, float* __restrict__ pl, float* __restrict__ po)
{
    int s  = blockIdx.x;
    int t  = threadIdx.x;
    int h  = t >> 3;
    int sl = t & 7;
    int r0 = s * RPB;

    __shared__ float sc[NHEAD][RPB + 1];

    float* knew = out + EDIM;
    float* vnew = out + (size_t)EDIM * (1 + LTOT);

    // q fragment (16 floats, prescaled); q_f is small and L2-resident
    float qr[16];
#pragma unroll
    for (int j = 0; j < 4; ++j) {
        f32x4 v = ld4(q_f + (t * 4 + j) * 4);
        qr[j*4+0] = v.x * SCALE; qr[j*4+1] = v.y * SCALE;
        qr[j*4+2] = v.z * SCALE; qr[j*4+3] = v.w * SCALE;
    }

    // ---- K pass ----
    for (int i = 0; i < RPB; ++i) {
        int row = r0 + i;
        f32x4 a[4];
        if (row < LCACHE) {
            const float* src = kc + (size_t)row * EDIM + t * 16;
#pragma unroll
            for (int j = 0; j < 4; ++j) a[j] = ntload4(src + j * 4);
            float* dst = knew + (size_t)row * EDIM + t * 16;
#pragma unroll
            for (int j = 0; j < 4; ++j) ntstore4(dst + j * 4, a[j]);
        } else {
            const float* src = knew + (size_t)row * EDIM + t * 16;
#pragma unroll
            for (int j = 0; j < 4; ++j) a[j] = ld4(src + j * 4);
        }
        float d = 0.f;
#pragma unroll
        for (int j = 0; j < 4; ++j)
            d += a[j].x * qr[j*4+0] + a[j].y * qr[j*4+1] +
                 a[j].z * qr[j*4+2] + a[j].w * qr[j*4+3];
        d += __shfl_xor(d, 1); d += __shfl_xor(d, 2); d += __shfl_xor(d, 4);
        if (sl == 0) sc[h][i] = d;
    }
    __syncthreads();

    // ---- per-head local softmax (8 lanes/head, 1 row each) ----
    float v0 = sc[h][sl];
    float m = v0;
    m = fmaxf(m, __shfl_xor(m, 1));
    m = fmaxf(m, __shfl_xor(m, 2));
    m = fmaxf(m, __shfl_xor(m, 4));
    float p0 = __expf(v0 - m);
    sc[h][sl] = p0;
    float l = p0;
    l += __shfl_xor(l, 1); l += __shfl_xor(l, 2); l += __shfl_xor(l, 4);
    if (sl == 0) {
        pm[(size_t)h * NSPLIT + s] = m;
        pl[(size_t)h * NSPLIT + s] = l;
    }
    __syncthreads();

    // ---- V pass ----
    float acc[16];
#pragma unroll
    for (int e = 0; e < 16; ++e) acc[e] = 0.f;
    for (int i = 0; i < RPB; ++i) {
        int row = r0 + i;
        f32x4 a[4];
        if (row < LCACHE) {
            const float* src = vc + (size_t)row * EDIM + t * 16;
#pragma unroll
            for (int j = 0; j < 4; ++j) a[j] = ntload4(src + j * 4);
            float* dst = vnew + (size_t)row * EDIM + t * 16;
#pragma unroll
            for (int j = 0; j < 4; ++j) ntstore4(dst + j * 4, a[j]);
        } else {
            const float* src = vnew + (size_t)row * EDIM + t * 16;
#pragma unroll
            for (int j = 0; j < 4; ++j) a[j] = ld4(src + j * 4);
        }
        float w = sc[h][i];
#pragma unroll
        for (int j = 0; j < 4; ++j) {
            acc[j*4+0] += w * a[j].x; acc[j*4+1] += w * a[j].y;
            acc[j*4+2] += w * a[j].z; acc[j*4+3] += w * a[j].w;
        }
    }
    float* pd = po + ((size_t)s * NHEAD + h) * DHEAD + sl * 16;
#pragma unroll
    for (int j = 0; j < 4; ++j) {
        f32x4 v; v.x = acc[j*4+0]; v.y = acc[j*4+1];
        v.z = acc[j*4+2]; v.w = acc[j*4+3];
        *(f32x4*)(pd + j * 4) = v;
    }
}

// ---------------------------------------------------------------------------
// Kernel 3: combine split partials -> attn vector.  grid 32 heads, 512 thr.
// 4 groups of 128 threads each handle NSPLIT/4 splits; LDS reduce.
// ---------------------------------------------------------------------------
__global__ __launch_bounds__(512) void combine_kernel(
    const float* __restrict__ pm, const float* __restrict__ pl,
    const float* __restrict__ po, float* __restrict__ attn_f)
{
    int h = blockIdx.x;
    int t = threadIdx.x;
    int g = t >> 7;       // 0..3
    int d = t & 127;

    __shared__ float sm[NSPLIT];
    __shared__ float sw[NSPLIT];
    __shared__ float wm[8];
    __shared__ float red[4][DHEAD];
    __shared__ float redl[4];

    for (int i = t; i < NSPLIT; i += 512) {
        sm[i] = pm[(size_t)h * NSPLIT + i];
        sw[i] = pl[(size_t)h * NSPLIT + i];
    }
    __syncthreads();

    // global max over splits
    float M = -1e30f;
    for (int i = t; i < NSPLIT; i += 512) M = fmaxf(M, sm[i]);
    for (int msk = 32; msk; msk >>= 1) M = fmaxf(M, __shfl_xor(M, msk));
    if ((t & 63) == 0) wm[t >> 6] = M;
    __syncthreads();
    M = wm[0];
#pragma unroll
    for (int i = 1; i < 8; ++i) M = fmaxf(M, wm[i]);

    // per-group accumulate
    float L = 0.f, o = 0.f;
    for (int i = g; i < NSPLIT; i += 4) {
        float w = __expf(sm[i] - M);
        L += sw[i] * w;
        o += w * po[((size_t)i * NHEAD + h) * DHEAD + d];
    }
    red[g][d] = o;
    if (d == 0) redl[g] = L;
    __syncthreads();
    if (g == 0) {
        float oo = red[0][d] + red[1][d] + red[2][d] + red[3][d];
        float LL = redl[0] + redl[1] + redl[2] + redl[3];
        attn_f[h * DHEAD + d] = oo / LL;
    }
}

// ---------------------------------------------------------------------------
// Kernel 4: output projection out[row] = attn . Wq[row] + bq[row]
// ---------------------------------------------------------------------------
__global__ __launch_bounds__(256) void proj_kernel(
    const float* __restrict__ attn_f, const float* __restrict__ Wq,
    const float* __restrict__ bq, float* __restrict__ out)
{
    int row = blockIdx.x;
    const float* wr = Wq + (size_t)row * EDIM;
    int t = threadIdx.x;
    float sum = 0.f;
#pragma unroll
    for (int i = 0; i < 4; ++i) {
        int j = (i * 256 + t) * 4;
        f32x4 w = ld4(wr + j);
        f32x4 a = ld4(attn_f + j);
        sum += w.x * a.x + w.y * a.y + w.z * a.z + w.w * a.w;
    }
    for (int m = 32; m; m >>= 1) sum += __shfl_xor(sum, m);
    __shared__ float wsum[4];
    if ((t & 63) == 0) wsum[t >> 6] = sum;
    __syncthreads();
    if (t == 0)
        out[row] = wsum[0] + wsum[1] + wsum[2] + wsum[3] + bq[row];
}

// ---------------------------------------------------------------------------
extern "C" void kernel_launch(void* const* d_in, const int* in_sizes, int n_in,
                              void* d_out, int out_size, void* d_ws, size_t ws_size,
                              hipStream_t stream)
{
    const float* seq = (const float*)d_in[0];
    const float* kc  = (const float*)d_in[1];
    const float* vc  = (const float*)d_in[2];
    const float* Wq  = (const float*)d_in[3];
    const float* bq  = (const float*)d_in[4];
    const float* Wk  = (const float*)d_in[5];
    const float* bk  = (const float*)d_in[6];
    const float* Wv  = (const float*)d_in[7];
    const float* bv  = (const float*)d_in[8];
    float* out = (float*)d_out;

    float* wsf    = (float*)d_ws;
    float* q_f    = wsf;                        // 4096
    float* attn_f = wsf + 4096;                 // 4096
    float* pm     = wsf + 8192;                 // 32*1024
    float* pl     = pm + NHEAD * NSPLIT;        // 32*1024
    float* po     = pl + NHEAD * NSPLIT;        // 1024*32*128

    hipLaunchKernelGGL(qkv_kernel, dim3(3 * 4096), dim3(256), 0, stream,
                       seq, Wq, bq, Wk, bk, Wv, bv, q_f, out);
    hipLaunchKernelGGL(fused_copy_attn, dim3(NSPLIT), dim3(256), 0, stream,
                       kc, vc, q_f, out, pm, pl, po);
    hipLaunchKernelGGL(combine_kernel, dim3(NHEAD), dim3(512), 0, stream,
                       pm, pl, po, attn_f);
    hipLaunchKernelGGL(proj_kernel, dim3(4096), dim3(256), 0, stream,
                       attn_f, Wq, bq, out);
}

// Round 4
// 229.168 us; speedup vs baseline: 2.3555x; 2.3555x over previous
//
#include <hip/hip_runtime.h>

#define EDIM   4096
#define NHEAD  32
#define DHEAD  128
#define LCACHE 8191
#define LTOT   8192
#define NSPLIT 1024
#define RPB    8     // rows per split (NSPLIT*RPB == LTOT)

#define SCALE 0.08838834764831845f  // 1/sqrt(128)

typedef float __attribute__((ext_vector_type(4))) f32x4;

__device__ __forceinline__ f32x4 ntload4(const float* p) {
    return __builtin_nontemporal_load((const f32x4*)p);
}
__device__ __forceinline__ void ntstore4(float* p, f32x4 v) {
    __builtin_nontemporal_store(v, (f32x4*)p);
}
__device__ __forceinline__ f32x4 ld4(const float* p) {
    return *(const f32x4*)p;
}

// ---------------------------------------------------------------------------
// Kernel 1: q/k/v GEMVs (f32). grid 12288: sel = idx>>12, row = idx & 4095.
// Coalesced: thread t reads 16B chunk (i*256+t)*4. Wk/Wv non-temporal.
// ---------------------------------------------------------------------------
__global__ __launch_bounds__(256) void qkv_kernel(
    const float* __restrict__ seq,
    const float* __restrict__ Wq, const float* __restrict__ bq,
    const float* __restrict__ Wk, const float* __restrict__ bk,
    const float* __restrict__ Wv, const float* __restrict__ bv,
    float* __restrict__ q_f, float* __restrict__ out)
{
    int row = blockIdx.x & 4095;
    int sel = blockIdx.x >> 12;
    const float* W = sel == 0 ? Wq : (sel == 1 ? Wk : Wv);
    const float* b = sel == 0 ? bq : (sel == 1 ? bk : bv);
    const float* wr = W + (size_t)row * EDIM;
    int t = threadIdx.x;

    float sum = 0.f;
#pragma unroll
    for (int i = 0; i < 4; ++i) {
        int j = (i * 256 + t) * 4;
        f32x4 w = (sel == 0) ? ld4(wr + j) : ntload4(wr + j);
        f32x4 s = ld4(seq + j);
        sum += w.x * s.x + w.y * s.y + w.z * s.z + w.w * s.w;
    }
    for (int m = 32; m; m >>= 1) sum += __shfl_xor(sum, m);
    __shared__ float wsum[4];
    if ((t & 63) == 0) wsum[t >> 6] = sum;
    __syncthreads();
    if (t == 0) {
        float total = wsum[0] + wsum[1] + wsum[2] + wsum[3] + b[row];
        if (sel == 0)      q_f[row] = total;
        else if (sel == 1) out[(size_t)EDIM * (1 + LCACHE) + row] = total;
        else               out[(size_t)EDIM * (1 + LTOT + LCACHE) + row] = total;
    }
}

// ---------------------------------------------------------------------------
// Kernel 2: fused KV-copy + flash-decode partials, instruction-coalesced.
// grid NSPLIT=1024, block 256.  Thread t, chunk j: owns global elements
// (j*256+t)*4 .. +4 of each row -> head j*8+(t>>5), dims 4*(t&31) .. +4.
// K pass: NT-read kc row (coalesced), NT-write k_new, 4 partial dots reduced
// over 32 contiguous lanes. Per-head softmax over RPB=8 rows. V pass: same
// loads + PV accumulate; po stored as full 4096-vector per split (coalesced).
// ---------------------------------------------------------------------------
__global__ __launch_bounds__(256) void fused_copy_attn(
    const float* __restrict__ kc, const float* __restrict__ vc,
    const float* __restrict__ q_f, float* __restrict__ out,
    float* __restrict__ pm, float* __restrict__ pl, float* __restrict__ po)
{
    int s  = blockIdx.x;
    int t  = threadIdx.x;
    int g  = t >> 5;     // 0..7: head group
    int r0 = s * RPB;

    __shared__ float sc[NHEAD][RPB + 1];

    float* knew = out + EDIM;
    float* vnew = out + (size_t)EDIM * (1 + LTOT);

    // q fragment: 4 chunks of 4 floats, matching the coalesced ownership
    float qr[16];
#pragma unroll
    for (int j = 0; j < 4; ++j) {
        f32x4 v = ld4(q_f + (j * 256 + t) * 4);
        qr[j*4+0] = v.x * SCALE; qr[j*4+1] = v.y * SCALE;
        qr[j*4+2] = v.z * SCALE; qr[j*4+3] = v.w * SCALE;
    }

    // ---- K pass ----
    for (int i = 0; i < RPB; ++i) {
        int row = r0 + i;
        f32x4 a[4];
        if (row < LCACHE) {
            const float* src = kc + (size_t)row * EDIM;
#pragma unroll
            for (int j = 0; j < 4; ++j) a[j] = ntload4(src + (j * 256 + t) * 4);
            float* dst = knew + (size_t)row * EDIM;
#pragma unroll
            for (int j = 0; j < 4; ++j) ntstore4(dst + (j * 256 + t) * 4, a[j]);
        } else {
            const float* src = knew + (size_t)row * EDIM;
#pragma unroll
            for (int j = 0; j < 4; ++j) a[j] = ld4(src + (j * 256 + t) * 4);
        }
        float pd[4];
#pragma unroll
        for (int j = 0; j < 4; ++j)
            pd[j] = a[j].x * qr[j*4+0] + a[j].y * qr[j*4+1] +
                    a[j].z * qr[j*4+2] + a[j].w * qr[j*4+3];
#pragma unroll
        for (int msk = 1; msk <= 16; msk <<= 1) {
#pragma unroll
            for (int j = 0; j < 4; ++j) pd[j] += __shfl_xor(pd[j], msk);
        }
        if ((t & 31) == 0) {
#pragma unroll
            for (int j = 0; j < 4; ++j) sc[j * 8 + g][i] = pd[j];
        }
    }
    __syncthreads();

    // ---- per-head local softmax (8 lanes/head, 1 row each) ----
    {
        int h  = t >> 3;
        int sl = t & 7;
        float v0 = sc[h][sl];
        float m = v0;
        m = fmaxf(m, __shfl_xor(m, 1));
        m = fmaxf(m, __shfl_xor(m, 2));
        m = fmaxf(m, __shfl_xor(m, 4));
        float p0 = __expf(v0 - m);
        sc[h][sl] = p0;
        float l = p0;
        l += __shfl_xor(l, 1); l += __shfl_xor(l, 2); l += __shfl_xor(l, 4);
        if (sl == 0) {
            pm[(size_t)h * NSPLIT + s] = m;
            pl[(size_t)h * NSPLIT + s] = l;
        }
    }
    __syncthreads();

    // ---- V pass ----
    f32x4 acc[4];
#pragma unroll
    for (int j = 0; j < 4; ++j) acc[j] = (f32x4){0.f, 0.f, 0.f, 0.f};
    for (int i = 0; i < RPB; ++i) {
        int row = r0 + i;
        f32x4 a[4];
        if (row < LCACHE) {
            const float* src = vc + (size_t)row * EDIM;
#pragma unroll
            for (int j = 0; j < 4; ++j) a[j] = ntload4(src + (j * 256 + t) * 4);
            float* dst = vnew + (size_t)row * EDIM;
#pragma unroll
            for (int j = 0; j < 4; ++j) ntstore4(dst + (j * 256 + t) * 4, a[j]);
        } else {
            const float* src = vnew + (size_t)row * EDIM;
#pragma unroll
            for (int j = 0; j < 4; ++j) a[j] = ld4(src + (j * 256 + t) * 4);
        }
#pragma unroll
        for (int j = 0; j < 4; ++j) {
            float w = sc[j * 8 + g][i];
            acc[j] += w * a[j];
        }
    }
#pragma unroll
    for (int j = 0; j < 4; ++j)
        *(f32x4*)(po + (size_t)s * EDIM + (j * 256 + t) * 4) = acc[j];
}

// ---------------------------------------------------------------------------
// Kernel 3: combine split partials -> attn vector.  grid 32 heads, 512 thr.
// po layout: [split][4096], head h at offset h*128.
// ---------------------------------------------------------------------------
__global__ __launch_bounds__(512) void combine_kernel(
    const float* __restrict__ pm, const float* __restrict__ pl,
    const float* __restrict__ po, float* __restrict__ attn_f)
{
    int h = blockIdx.x;
    int t = threadIdx.x;
    int g = t >> 7;       // 0..3
    int d = t & 127;

    __shared__ float sm[NSPLIT];
    __shared__ float sw[NSPLIT];
    __shared__ float wm[8];
    __shared__ float red[4][DHEAD];
    __shared__ float redl[4];

    for (int i = t; i < NSPLIT; i += 512) {
        sm[i] = pm[(size_t)h * NSPLIT + i];
        sw[i] = pl[(size_t)h * NSPLIT + i];
    }
    __syncthreads();

    float M = -1e30f;
    for (int i = t; i < NSPLIT; i += 512) M = fmaxf(M, sm[i]);
    for (int msk = 32; msk; msk >>= 1) M = fmaxf(M, __shfl_xor(M, msk));
    if ((t & 63) == 0) wm[t >> 6] = M;
    __syncthreads();
    M = wm[0];
#pragma unroll
    for (int i = 1; i < 8; ++i) M = fmaxf(M, wm[i]);

    float L = 0.f, o = 0.f;
    for (int i = g; i < NSPLIT; i += 4) {
        float w = __expf(sm[i] - M);
        L += sw[i] * w;
        o += w * po[(size_t)i * EDIM + h * DHEAD + d];
    }
    red[g][d] = o;
    if (d == 0) redl[g] = L;
    __syncthreads();
    if (g == 0) {
        float oo = red[0][d] + red[1][d] + red[2][d] + red[3][d];
        float LL = redl[0] + redl[1] + redl[2] + redl[3];
        attn_f[h * DHEAD + d] = oo / LL;
    }
}

// ---------------------------------------------------------------------------
// Kernel 4: output projection out[row] = attn . Wq[row] + bq[row]
// ---------------------------------------------------------------------------
__global__ __launch_bounds__(256) void proj_kernel(
    const float* __restrict__ attn_f, const float* __restrict__ Wq,
    const float* __restrict__ bq, float* __restrict__ out)
{
    int row = blockIdx.x;
    const float* wr = Wq + (size_t)row * EDIM;
    int t = threadIdx.x;
    float sum = 0.f;
#pragma unroll
    for (int i = 0; i < 4; ++i) {
        int j = (i * 256 + t) * 4;
        f32x4 w = ld4(wr + j);
        f32x4 a = ld4(attn_f + j);
        sum += w.x * a.x + w.y * a.y + w.z * a.z + w.w * a.w;
    }
    for (int m = 32; m; m >>= 1) sum += __shfl_xor(sum, m);
    __shared__ float wsum[4];
    if ((t & 63) == 0) wsum[t >> 6] = sum;
    __syncthreads();
    if (t == 0)
        out[row] = wsum[0] + wsum[1] + wsum[2] + wsum[3] + bq[row];
}

// ---------------------------------------------------------------------------
extern "C" void kernel_launch(void* const* d_in, const int* in_sizes, int n_in,
                              void* d_out, int out_size, void* d_ws, size_t ws_size,
                              hipStream_t stream)
{
    const float* seq = (const float*)d_in[0];
    const float* kc  = (const float*)d_in[1];
    const float* vc  = (const float*)d_in[2];
    const float* Wq  = (const float*)d_in[3];
    const float* bq  = (const float*)d_in[4];
    const float* Wk  = (const float*)d_in[5];
    const float* bk  = (const float*)d_in[6];
    const float* Wv  = (const float*)d_in[7];
    const float* bv  = (const float*)d_in[8];
    float* out = (float*)d_out;

    float* wsf    = (float*)d_ws;
    float* q_f    = wsf;                        // 4096
    float* attn_f = wsf + 4096;                 // 4096
    float* pm     = wsf + 8192;                 // 32*1024
    float* pl     = pm + NHEAD * NSPLIT;        // 32*1024
    float* po     = pl + NHEAD * NSPLIT;        // 1024*4096

    hipLaunchKernelGGL(qkv_kernel, dim3(3 * 4096), dim3(256), 0, stream,
                       seq, Wq, bq, Wk, bk, Wv, bv, q_f, out);
    hipLaunchKernelGGL(fused_copy_attn, dim3(NSPLIT), dim3(256), 0, stream,
                       kc, vc, q_f, out, pm, pl, po);
    hipLaunchKernelGGL(combine_kernel, dim3(NHEAD), dim3(512), 0, stream,
                       pm, pl, po, attn_f);
    hipLaunchKernelGGL(proj_kernel, dim3(4096), dim3(256), 0, stream,
                       attn_f, Wq, bq, out);
}

// Round 5
// 172.579 us; speedup vs baseline: 3.1278x; 1.3279x over previous
//
#include <hip/hip_runtime.h>

#define EDIM   4096
#define NHEAD  32
#define DHEAD  128
#define LCACHE 8191
#define LTOT   8192
#define NSPLIT 1024
#define RPB    8     // rows per split (NSPLIT*RPB == LTOT)
#define NGRP   8     // combine stage-1 groups
#define SPG    128   // splits per group (NSPLIT/NGRP)

#define SCALE 0.08838834764831845f  // 1/sqrt(128)

typedef float __attribute__((ext_vector_type(4))) f32x4;

__device__ __forceinline__ f32x4 ntload4(const float* p) {
    return __builtin_nontemporal_load((const f32x4*)p);
}
__device__ __forceinline__ void ntstore4(float* p, f32x4 v) {
    __builtin_nontemporal_store(v, (f32x4*)p);
}
__device__ __forceinline__ f32x4 ld4(const float* p) {
    return *(const f32x4*)p;
}

// ---------------------------------------------------------------------------
// Kernel 1: q/k/v GEMVs. One 64-lane wave per output row, 4 rows/block.
// grid 3072: global row idx = blockIdx*4 + wave; sel = idx>>12, row = idx&4095.
// No barriers: pure wave-shuffle reduction. Wk/Wv non-temporal.
// ---------------------------------------------------------------------------
__global__ __launch_bounds__(256) void qkv_kernel(
    const float* __restrict__ seq,
    const float* __restrict__ Wq, const float* __restrict__ bq,
    const float* __restrict__ Wk, const float* __restrict__ bk,
    const float* __restrict__ Wv, const float* __restrict__ bv,
    float* __restrict__ q_f, float* __restrict__ out)
{
    int idx  = blockIdx.x * 4 + (threadIdx.x >> 6);
    int lane = threadIdx.x & 63;
    int sel  = idx >> 12;
    int row  = idx & 4095;
    const float* W = sel == 0 ? Wq : (sel == 1 ? Wk : Wv);
    const float* b = sel == 0 ? bq : (sel == 1 ? bk : bv);
    const float* wr = W + (size_t)row * EDIM;

    float sum = 0.f;
#pragma unroll
    for (int i = 0; i < 16; ++i) {
        int c = (i * 64 + lane) * 4;
        f32x4 w = (sel == 0) ? ld4(wr + c) : ntload4(wr + c);
        f32x4 s = ld4(seq + c);
        sum += w.x * s.x + w.y * s.y + w.z * s.z + w.w * s.w;
    }
#pragma unroll
    for (int m = 32; m; m >>= 1) sum += __shfl_xor(sum, m);
    if (lane == 0) {
        float total = sum + b[row];
        if (sel == 0)      q_f[row] = total;
        else if (sel == 1) out[(size_t)EDIM * (1 + LCACHE) + row] = total;
        else               out[(size_t)EDIM * (1 + LTOT + LCACHE) + row] = total;
    }
}

// ---------------------------------------------------------------------------
// Kernel 2: fused KV-copy + flash-decode partials, instruction-coalesced.
// grid NSPLIT=1024, block 256.  Thread t, chunk j: owns elements
// (j*256+t)*4.. of each row -> head j*8+(t>>5), dims 4*(t&31)..
// po stored [head][split][128] so combine streams contiguously.
// ---------------------------------------------------------------------------
__global__ __launch_bounds__(256) void fused_copy_attn(
    const float* __restrict__ kc, const float* __restrict__ vc,
    const float* __restrict__ q_f, float* __restrict__ out,
    float* __restrict__ pm, float* __restrict__ pl, float* __restrict__ po)
{
    int s  = blockIdx.x;
    int t  = threadIdx.x;
    int g  = t >> 5;     // 0..7: head sub-group
    int r0 = s * RPB;

    __shared__ float sc[NHEAD][RPB + 1];

    float* knew = out + EDIM;
    float* vnew = out + (size_t)EDIM * (1 + LTOT);

    float qr[16];
#pragma unroll
    for (int j = 0; j < 4; ++j) {
        f32x4 v = ld4(q_f + (j * 256 + t) * 4);
        qr[j*4+0] = v.x * SCALE; qr[j*4+1] = v.y * SCALE;
        qr[j*4+2] = v.z * SCALE; qr[j*4+3] = v.w * SCALE;
    }

    // ---- K pass ----
    for (int i = 0; i < RPB; ++i) {
        int row = r0 + i;
        f32x4 a[4];
        if (row < LCACHE) {
            const float* src = kc + (size_t)row * EDIM;
#pragma unroll
            for (int j = 0; j < 4; ++j) a[j] = ntload4(src + (j * 256 + t) * 4);
            float* dst = knew + (size_t)row * EDIM;
#pragma unroll
            for (int j = 0; j < 4; ++j) ntstore4(dst + (j * 256 + t) * 4, a[j]);
        } else {
            const float* src = knew + (size_t)row * EDIM;
#pragma unroll
            for (int j = 0; j < 4; ++j) a[j] = ld4(src + (j * 256 + t) * 4);
        }
        float pd[4];
#pragma unroll
        for (int j = 0; j < 4; ++j)
            pd[j] = a[j].x * qr[j*4+0] + a[j].y * qr[j*4+1] +
                    a[j].z * qr[j*4+2] + a[j].w * qr[j*4+3];
#pragma unroll
        for (int msk = 1; msk <= 16; msk <<= 1) {
#pragma unroll
            for (int j = 0; j < 4; ++j) pd[j] += __shfl_xor(pd[j], msk);
        }
        if ((t & 31) == 0) {
#pragma unroll
            for (int j = 0; j < 4; ++j) sc[j * 8 + g][i] = pd[j];
        }
    }
    __syncthreads();

    // ---- per-head local softmax ----
    {
        int h  = t >> 3;
        int sl = t & 7;
        float v0 = sc[h][sl];
        float m = v0;
        m = fmaxf(m, __shfl_xor(m, 1));
        m = fmaxf(m, __shfl_xor(m, 2));
        m = fmaxf(m, __shfl_xor(m, 4));
        float p0 = __expf(v0 - m);
        sc[h][sl] = p0;
        float l = p0;
        l += __shfl_xor(l, 1); l += __shfl_xor(l, 2); l += __shfl_xor(l, 4);
        if (sl == 0) {
            pm[(size_t)h * NSPLIT + s] = m;
            pl[(size_t)h * NSPLIT + s] = l;
        }
    }
    __syncthreads();

    // ---- V pass ----
    f32x4 acc[4];
#pragma unroll
    for (int j = 0; j < 4; ++j) acc[j] = (f32x4){0.f, 0.f, 0.f, 0.f};
    for (int i = 0; i < RPB; ++i) {
        int row = r0 + i;
        f32x4 a[4];
        if (row < LCACHE) {
            const float* src = vc + (size_t)row * EDIM;
#pragma unroll
            for (int j = 0; j < 4; ++j) a[j] = ntload4(src + (j * 256 + t) * 4);
            float* dst = vnew + (size_t)row * EDIM;
#pragma unroll
            for (int j = 0; j < 4; ++j) ntstore4(dst + (j * 256 + t) * 4, a[j]);
        } else {
            const float* src = vnew + (size_t)row * EDIM;
#pragma unroll
            for (int j = 0; j < 4; ++j) a[j] = ld4(src + (j * 256 + t) * 4);
        }
#pragma unroll
        for (int j = 0; j < 4; ++j) {
            float w = sc[j * 8 + g][i];
            acc[j] += w * a[j];
        }
    }
    int lane32 = t & 31;
#pragma unroll
    for (int j = 0; j < 4; ++j) {
        int head = j * 8 + g;
        *(f32x4*)(po + ((size_t)head * NSPLIT + s) * DHEAD + lane32 * 4) = acc[j];
    }
}

// ---------------------------------------------------------------------------
// Kernel 3a: combine stage 1.  grid (NHEAD, NGRP), 512 thr.
// Block (h,grp): 128 splits; sub-group sg=t>>7 strides splits; d=t&127.
// Outputs per (h,grp): gm (max), gl (sum), go[128].
// ---------------------------------------------------------------------------
__global__ __launch_bounds__(512) void combine1_kernel(
    const float* __restrict__ pm, const float* __restrict__ pl,
    const float* __restrict__ po,
    float* __restrict__ gm, float* __restrict__ gl, float* __restrict__ go)
{
    int h   = blockIdx.x;
    int grp = blockIdx.y;
    int t   = threadIdx.x;
    int sg  = t >> 7;
    int d   = t & 127;
    int s0  = grp * SPG;

    __shared__ float sm[SPG], sw[SPG];
    __shared__ float red[4][DHEAD];
    __shared__ float redl[4];

    if (t < SPG) {
        sm[t] = pm[(size_t)h * NSPLIT + s0 + t];
        sw[t] = pl[(size_t)h * NSPLIT + s0 + t];
    }
    __syncthreads();

    float M = -1e30f;
    for (int i = 0; i < SPG; ++i) M = fmaxf(M, sm[i]);

    float o = 0.f, L = 0.f;
    for (int i = sg; i < SPG; i += 4) {
        float w = __expf(sm[i] - M);
        o += w * po[((size_t)h * NSPLIT + s0 + i) * DHEAD + d];
        L += w * sw[i];
    }
    red[sg][d] = o;
    if (d == 0) redl[sg] = L;
    __syncthreads();
    if (sg == 0) {
        float oo = red[0][d] + red[1][d] + red[2][d] + red[3][d];
        go[((size_t)h * NGRP + grp) * DHEAD + d] = oo;
        if (d == 0) {
            gm[h * NGRP + grp] = M;
            gl[h * NGRP + grp] = redl[0] + redl[1] + redl[2] + redl[3];
        }
    }
}

// ---------------------------------------------------------------------------
// Kernel 3b: combine stage 2.  grid NHEAD, 128 thr: merge NGRP groups.
// ---------------------------------------------------------------------------
__global__ __launch_bounds__(128) void combine2_kernel(
    const float* __restrict__ gm, const float* __restrict__ gl,
    const float* __restrict__ go, float* __restrict__ attn_f)
{
    int h = blockIdx.x;
    int d = threadIdx.x;
    float M = -1e30f;
#pragma unroll
    for (int g = 0; g < NGRP; ++g) M = fmaxf(M, gm[h * NGRP + g]);
    float o = 0.f, L = 0.f;
#pragma unroll
    for (int g = 0; g < NGRP; ++g) {
        float w = __expf(gm[h * NGRP + g] - M);
        o += w * go[((size_t)h * NGRP + g) * DHEAD + d];
        L += w * gl[h * NGRP + g];
    }
    attn_f[h * DHEAD + d] = o / L;
}

// ---------------------------------------------------------------------------
// Kernel 4: output projection. One wave per row, 4 rows/block, grid 1024.
// ---------------------------------------------------------------------------
__global__ __launch_bounds__(256) void proj_kernel(
    const float* __restrict__ attn_f, const float* __restrict__ Wq,
    const float* __restrict__ bq, float* __restrict__ out)
{
    int row  = blockIdx.x * 4 + (threadIdx.x >> 6);
    int lane = threadIdx.x & 63;
    const float* wr = Wq + (size_t)row * EDIM;

    float sum = 0.f;
#pragma unroll
    for (int i = 0; i < 16; ++i) {
        int c = (i * 64 + lane) * 4;
        f32x4 w = ld4(wr + c);
        f32x4 a = ld4(attn_f + c);
        sum += w.x * a.x + w.y * a.y + w.z * a.z + w.w * a.w;
    }
#pragma unroll
    for (int m = 32; m; m >>= 1) sum += __shfl_xor(sum, m);
    if (lane == 0)
        out[row] = sum + bq[row];
}

// ---------------------------------------------------------------------------
extern "C" void kernel_launch(void* const* d_in, const int* in_sizes, int n_in,
                              void* d_out, int out_size, void* d_ws, size_t ws_size,
                              hipStream_t stream)
{
    const float* seq = (const float*)d_in[0];
    const float* kc  = (const float*)d_in[1];
    const float* vc  = (const float*)d_in[2];
    const float* Wq  = (const float*)d_in[3];
    const float* bq  = (const float*)d_in[4];
    const float* Wk  = (const float*)d_in[5];
    const float* bk  = (const float*)d_in[6];
    const float* Wv  = (const float*)d_in[7];
    const float* bv  = (const float*)d_in[8];
    float* out = (float*)d_out;

    float* wsf    = (float*)d_ws;
    float* q_f    = wsf;                        // 4096
    float* attn_f = wsf + 4096;                 // 4096
    float* pm     = wsf + 8192;                 // 32*1024
    float* pl     = pm + NHEAD * NSPLIT;        // 32*1024
    float* gm     = pl + NHEAD * NSPLIT;        // 32*8
    float* gl     = gm + NHEAD * NGRP;          // 32*8
    float* go     = gl + NHEAD * NGRP;          // 32*8*128
    float* po     = go + NHEAD * NGRP * DHEAD;  // 32*1024*128

    hipLaunchKernelGGL(qkv_kernel, dim3(3072), dim3(256), 0, stream,
                       seq, Wq, bq, Wk, bk, Wv, bv, q_f, out);
    hipLaunchKernelGGL(fused_copy_attn, dim3(NSPLIT), dim3(256), 0, stream,
                       kc, vc, q_f, out, pm, pl, po);
    hipLaunchKernelGGL(combine1_kernel, dim3(NHEAD, NGRP), dim3(512), 0, stream,
                       pm, pl, po, gm, gl, go);
    hipLaunchKernelGGL(combine2_kernel, dim3(NHEAD), dim3(128), 0, stream,
                       gm, gl, go, attn_f);
    hipLaunchKernelGGL(proj_kernel, dim3(1024), dim3(256), 0, stream,
                       attn_f, Wq, bq, out);
}

// Round 6
// 167.013 us; speedup vs baseline: 3.2321x; 1.0333x over previous
//
#include <hip/hip_runtime.h>

#define EDIM   4096
#define NHEAD  32
#define DHEAD  128
#define LCACHE 8191
#define LTOT   8192
#define NSPLIT 1024
#define RPB    8     // rows per split (NSPLIT*RPB == LTOT)
#define NGRP   8     // combine stage-1 groups
#define SPG    128   // splits per group (NSPLIT/NGRP)

#define SCALE 0.08838834764831845f  // 1/sqrt(128)

typedef float __attribute__((ext_vector_type(4))) f32x4;

__device__ __forceinline__ f32x4 ntload4(const float* p) {
    return __builtin_nontemporal_load((const f32x4*)p);
}
__device__ __forceinline__ void ntstore4(float* p, f32x4 v) {
    __builtin_nontemporal_store(v, (f32x4*)p);
}
__device__ __forceinline__ f32x4 ld4(const float* p) {
    return *(const f32x4*)p;
}

// ---------------------------------------------------------------------------
// Kernel 1: q/k/v GEMVs. One 64-lane wave per output row, 4 rows/block.
// ---------------------------------------------------------------------------
__global__ __launch_bounds__(256) void qkv_kernel(
    const float* __restrict__ seq,
    const float* __restrict__ Wq, const float* __restrict__ bq,
    const float* __restrict__ Wk, const float* __restrict__ bk,
    const float* __restrict__ Wv, const float* __restrict__ bv,
    float* __restrict__ q_f, float* __restrict__ out)
{
    int idx  = blockIdx.x * 4 + (threadIdx.x >> 6);
    int lane = threadIdx.x & 63;
    int sel  = idx >> 12;
    int row  = idx & 4095;
    const float* W = sel == 0 ? Wq : (sel == 1 ? Wk : Wv);
    const float* b = sel == 0 ? bq : (sel == 1 ? bk : bv);
    const float* wr = W + (size_t)row * EDIM;

    float sum = 0.f;
#pragma unroll
    for (int i = 0; i < 16; ++i) {
        int c = (i * 64 + lane) * 4;
        f32x4 w = (sel == 0) ? ld4(wr + c) : ntload4(wr + c);
        f32x4 s = ld4(seq + c);
        sum += w.x * s.x + w.y * s.y + w.z * s.z + w.w * s.w;
    }
#pragma unroll
    for (int m = 32; m; m >>= 1) sum += __shfl_xor(sum, m);
    if (lane == 0) {
        float total = sum + b[row];
        if (sel == 0)      q_f[row] = total;
        else if (sel == 1) out[(size_t)EDIM * (1 + LCACHE) + row] = total;
        else               out[(size_t)EDIM * (1 + LTOT + LCACHE) + row] = total;
    }
}

// ---------------------------------------------------------------------------
// Kernel 2: fused KV-copy + flash-decode, ONE-PASS online softmax.
// grid NSPLIT=1024, block 256.  Thread t, chunk j: owns elements
// (j*256+t)*4.. of each row -> head j*8+(t>>5), dims 4*(t&31)..
// Per row: prefetch next row's K+V (2-deep reg pipeline), NT-store copy,
// score butterfly over 32 lanes, online (m,l,acc) update.  NO barriers.
// ---------------------------------------------------------------------------
__global__ __launch_bounds__(256) void fused_copy_attn(
    const float* __restrict__ kc, const float* __restrict__ vc,
    const float* __restrict__ q_f, float* __restrict__ out,
    float* __restrict__ pm, float* __restrict__ pl, float* __restrict__ po)
{
    int s  = blockIdx.x;
    int t  = threadIdx.x;
    int g  = t >> 5;     // head sub-group 0..7
    int r0 = s * RPB;

    float* knew = out + EDIM;
    float* vnew = out + (size_t)EDIM * (1 + LTOT);

    int c0 = t * 4;          // chunk j at c0 + j*1024

    float qr[16];
#pragma unroll
    for (int j = 0; j < 4; ++j) {
        f32x4 v = ld4(q_f + j * 1024 + c0);
        qr[j*4+0] = v.x * SCALE; qr[j*4+1] = v.y * SCALE;
        qr[j*4+2] = v.z * SCALE; qr[j*4+3] = v.w * SCALE;
    }

    float m[4], l[4];
    f32x4 acc[4];
#pragma unroll
    for (int j = 0; j < 4; ++j) {
        m[j] = -1e30f; l[j] = 0.f;
        acc[j] = (f32x4){0.f, 0.f, 0.f, 0.f};
    }

    // prologue: load row r0
    f32x4 a[4], b[4];
    {
        const float* ksrc = (r0 < LCACHE) ? (kc + (size_t)r0 * EDIM)
                                          : (knew + (size_t)r0 * EDIM);
        const float* vsrc = (r0 < LCACHE) ? (vc + (size_t)r0 * EDIM)
                                          : (vnew + (size_t)r0 * EDIM);
#pragma unroll
        for (int j = 0; j < 4; ++j) a[j] = ntload4(ksrc + j * 1024 + c0);
#pragma unroll
        for (int j = 0; j < 4; ++j) b[j] = ntload4(vsrc + j * 1024 + c0);
    }

    for (int i = 0; i < RPB; ++i) {
        int row = r0 + i;
        // prefetch next row before consuming current
        f32x4 a2[4], b2[4];
        if (i + 1 < RPB) {
            int nrow = row + 1;
            const float* ksrc = (nrow < LCACHE) ? (kc + (size_t)nrow * EDIM)
                                                : (knew + (size_t)nrow * EDIM);
            const float* vsrc = (nrow < LCACHE) ? (vc + (size_t)nrow * EDIM)
                                                : (vnew + (size_t)nrow * EDIM);
#pragma unroll
            for (int j = 0; j < 4; ++j) a2[j] = ntload4(ksrc + j * 1024 + c0);
#pragma unroll
            for (int j = 0; j < 4; ++j) b2[j] = ntload4(vsrc + j * 1024 + c0);
        }
        // copy-out (waits only on current row's loads)
        if (row < LCACHE) {
            float* kd = knew + (size_t)row * EDIM;
            float* vd = vnew + (size_t)row * EDIM;
#pragma unroll
            for (int j = 0; j < 4; ++j) ntstore4(kd + j * 1024 + c0, a[j]);
#pragma unroll
            for (int j = 0; j < 4; ++j) ntstore4(vd + j * 1024 + c0, b[j]);
        }
        // scores: partial dot, butterfly all-reduce over 32 lanes
        float pd[4];
#pragma unroll
        for (int j = 0; j < 4; ++j)
            pd[j] = a[j].x * qr[j*4+0] + a[j].y * qr[j*4+1] +
                    a[j].z * qr[j*4+2] + a[j].w * qr[j*4+3];
#pragma unroll
        for (int msk = 1; msk <= 16; msk <<= 1) {
#pragma unroll
            for (int j = 0; j < 4; ++j) pd[j] += __shfl_xor(pd[j], msk);
        }
        // online softmax update per head
#pragma unroll
        for (int j = 0; j < 4; ++j) {
            float mn = fmaxf(m[j], pd[j]);
            float r  = __expf(m[j] - mn);
            float p  = __expf(pd[j] - mn);
            l[j] = l[j] * r + p;
            acc[j] = acc[j] * r + p * b[j];
            m[j] = mn;
        }
#pragma unroll
        for (int j = 0; j < 4; ++j) { a[j] = a2[j]; b[j] = b2[j]; }
    }

    int lane32 = t & 31;
    if (lane32 == 0) {
#pragma unroll
        for (int j = 0; j < 4; ++j) {
            int head = j * 8 + g;
            pm[(size_t)head * NSPLIT + s] = m[j];
            pl[(size_t)head * NSPLIT + s] = l[j];
        }
    }
#pragma unroll
    for (int j = 0; j < 4; ++j) {
        int head = j * 8 + g;
        *(f32x4*)(po + ((size_t)head * NSPLIT + s) * DHEAD + lane32 * 4) = acc[j];
    }
}

// ---------------------------------------------------------------------------
// Kernel 3a: combine stage 1.  grid (NHEAD, NGRP), 256 thr = 8 subgroups
// of 32 lanes; lane owns f32x4 of the head dim; subgroup strides splits.
// ---------------------------------------------------------------------------
__global__ __launch_bounds__(256) void combine1_kernel(
    const float* __restrict__ pm, const float* __restrict__ pl,
    const float* __restrict__ po,
    float* __restrict__ gm, float* __restrict__ gl, float* __restrict__ go)
{
    int h   = blockIdx.x;
    int grp = blockIdx.y;
    int t   = threadIdx.x;
    int sg  = t >> 5;    // 0..7
    int ln  = t & 31;
    int s0  = grp * SPG;

    __shared__ float sm[SPG], sw[SPG];
    __shared__ f32x4 red[8][32];
    __shared__ float redl[8];

    if (t < SPG) {
        sm[t] = pm[(size_t)h * NSPLIT + s0 + t];
        sw[t] = pl[(size_t)h * NSPLIT + s0 + t];
    }
    __syncthreads();

    float M = -1e30f;
#pragma unroll 8
    for (int i = 0; i < SPG; ++i) M = fmaxf(M, sm[i]);

    f32x4 o4 = (f32x4){0.f, 0.f, 0.f, 0.f};
    float L = 0.f;
    for (int i = sg; i < SPG; i += 8) {
        float w = __expf(sm[i] - M);
        o4 += w * ld4(po + ((size_t)h * NSPLIT + s0 + i) * DHEAD + ln * 4);
        L += w * sw[i];
    }
    red[sg][ln] = o4;
    if (ln == 0) redl[sg] = L;
    __syncthreads();
    if (sg == 0) {
        f32x4 oo = red[0][ln];
#pragma unroll
        for (int k = 1; k < 8; ++k) oo += red[k][ln];
        *(f32x4*)(go + ((size_t)h * NGRP + grp) * DHEAD + ln * 4) = oo;
        if (ln == 0) {
            float LL = redl[0];
#pragma unroll
            for (int k = 1; k < 8; ++k) LL += redl[k];
            gm[h * NGRP + grp] = M;
            gl[h * NGRP + grp] = LL;
        }
    }
}

// ---------------------------------------------------------------------------
// Kernel 3b: combine stage 2.  grid NHEAD, 128 thr: merge NGRP groups.
// ---------------------------------------------------------------------------
__global__ __launch_bounds__(128) void combine2_kernel(
    const float* __restrict__ gm, const float* __restrict__ gl,
    const float* __restrict__ go, float* __restrict__ attn_f)
{
    int h = blockIdx.x;
    int d = threadIdx.x;
    float M = -1e30f;
#pragma unroll
    for (int g = 0; g < NGRP; ++g) M = fmaxf(M, gm[h * NGRP + g]);
    float o = 0.f, L = 0.f;
#pragma unroll
    for (int g = 0; g < NGRP; ++g) {
        float w = __expf(gm[h * NGRP + g] - M);
        o += w * go[((size_t)h * NGRP + g) * DHEAD + d];
        L += w * gl[h * NGRP + g];
    }
    attn_f[h * DHEAD + d] = o / L;
}

// ---------------------------------------------------------------------------
// Kernel 4: output projection. One wave per row, 4 rows/block, grid 1024.
// ---------------------------------------------------------------------------
__global__ __launch_bounds__(256) void proj_kernel(
    const float* __restrict__ attn_f, const float* __restrict__ Wq,
    const float* __restrict__ bq, float* __restrict__ out)
{
    int row  = blockIdx.x * 4 + (threadIdx.x >> 6);
    int lane = threadIdx.x & 63;
    const float* wr = Wq + (size_t)row * EDIM;

    float sum = 0.f;
#pragma unroll
    for (int i = 0; i < 16; ++i) {
        int c = (i * 64 + lane) * 4;
        f32x4 w = ld4(wr + c);
        f32x4 a = ld4(attn_f + c);
        sum += w.x * a.x + w.y * a.y + w.z * a.z + w.w * a.w;
    }
#pragma unroll
    for (int m = 32; m; m >>= 1) sum += __shfl_xor(sum, m);
    if (lane == 0)
        out[row] = sum + bq[row];
}

// ---------------------------------------------------------------------------
extern "C" void kernel_launch(void* const* d_in, const int* in_sizes, int n_in,
                              void* d_out, int out_size, void* d_ws, size_t ws_size,
                              hipStream_t stream)
{
    const float* seq = (const float*)d_in[0];
    const float* kc  = (const float*)d_in[1];
    const float* vc  = (const float*)d_in[2];
    const float* Wq  = (const float*)d_in[3];
    const float* bq  = (const float*)d_in[4];
    const float* Wk  = (const float*)d_in[5];
    const float* bk  = (const float*)d_in[6];
    const float* Wv  = (const float*)d_in[7];
    const float* bv  = (const float*)d_in[8];
    float* out = (float*)d_out;

    float* wsf    = (float*)d_ws;
    float* q_f    = wsf;                        // 4096
    float* attn_f = wsf + 4096;                 // 4096
    float* pm     = wsf + 8192;                 // 32*1024
    float* pl     = pm + NHEAD * NSPLIT;        // 32*1024
    float* gm     = pl + NHEAD * NSPLIT;        // 32*8
    float* gl     = gm + NHEAD * NGRP;          // 32*8
    float* go     = gl + NHEAD * NGRP;          // 32*8*128
    float* po     = go + NHEAD * NGRP * DHEAD;  // 32*1024*128

    hipLaunchKernelGGL(qkv_kernel, dim3(3072), dim3(256), 0, stream,
                       seq, Wq, bq, Wk, bk, Wv, bv, q_f, out);
    hipLaunchKernelGGL(fused_copy_attn, dim3(NSPLIT), dim3(256), 0, stream,
                       kc, vc, q_f, out, pm, pl, po);
    hipLaunchKernelGGL(combine1_kernel, dim3(NHEAD, NGRP), dim3(256), 0, stream,
                       pm, pl, po, gm, gl, go);
    hipLaunchKernelGGL(combine2_kernel, dim3(NHEAD), dim3(128), 0, stream,
                       gm, gl, go, attn_f);
    hipLaunchKernelGGL(proj_kernel, dim3(1024), dim3(256), 0, stream,
                       attn_f, Wq, bq, out);
}